// Round 5
// baseline (400.006 us; speedup 1.0000x reference)
//
#include <hip/hip_runtime.h>
#include <math.h>

#define NA 8
#define SS 512
#define BROWS 32
#define TPB 4
#define NTHREADS 320

typedef __attribute__((ext_vector_type(8))) short bf16x8;
typedef __attribute__((ext_vector_type(4))) float f32x4;

static __device__ __forceinline__ unsigned short f2bf(float f) {
    union { float f; unsigned u; } v; v.f = f;
    unsigned r = v.u + 0x7FFFu + ((v.u >> 16) & 1u);
    return (unsigned short)(r >> 16);
}
static __device__ __forceinline__ float bf2f(unsigned short u) {
    union { unsigned u; float f; } v; v.u = ((unsigned)u) << 16; return v.f;
}

// ---- workspace layout (u16 units unless noted) ----
#define BP_OFF   0          // 81920 u16 : packed [512x160] fused first-layer W, bf16 frag layout
#define BP1_OFF  81920      // 20480 u16 : packed hw1_w1 [40->64 pad][320]
#define BP2_OFF  102400     // 3072 u16  : packed hw2_w1 [40->64 pad][40->48 pad]
#define BIAS0_BYTE 210944   // 160 f32   : fused first-layer bias [h1_b|b1_b|h2_b|hb_b]

__global__ void prep_kernel(const float* __restrict__ hw1_w0, const float* __restrict__ hb1_w,
                            const float* __restrict__ hw2_w0, const float* __restrict__ hb2_w0,
                            const float* __restrict__ hw1_w1, const float* __restrict__ hw2_w1,
                            const float* __restrict__ hw1_b0, const float* __restrict__ hb1_b,
                            const float* __restrict__ hw2_b0, const float* __restrict__ hb2_b0,
                            unsigned short* __restrict__ ws16, float* __restrict__ bias0) {
    int idx = blockIdx.x * blockDim.x + threadIdx.x;
    if (idx < 81920) {
        // Bp[((nt*16+kt)*64 + l)*8 + i] = Wc[kt*32+(l>>4)*8+i][nt*16+(l&15)]
        int i = idx & 7, l = (idx >> 3) & 63, t = idx >> 9;
        int kt = t & 15, nt = t >> 4;
        int k = kt * 32 + (l >> 4) * 8 + i;
        int n = nt * 16 + (l & 15);
        int seg = n / 40, c = n - seg * 40;
        const float* src = (seg == 0) ? hw1_w0 : (seg == 1) ? hb1_w : (seg == 2) ? hw2_w0 : hb2_w0;
        ws16[BP_OFF + idx] = f2bf(src[k * 40 + c]);
    } else if (idx < 81920 + 20480) {
        int j = idx - 81920;
        int i = j & 7, l = (j >> 3) & 63, t = j >> 9;   // t = nt1*2 + kt, t<40
        int kt = t & 1, nt = t >> 1;
        int k = kt * 32 + (l >> 4) * 8 + i;
        int n = nt * 16 + (l & 15);
        float v = (k < 40) ? hw1_w1[k * 320 + n] : 0.f;
        ws16[BP1_OFF + j] = f2bf(v);
    } else if (idx < 81920 + 20480 + 3072) {
        int j = idx - 102400;
        int i = j & 7, l = (j >> 3) & 63, t = j >> 9;   // t = nt2*2 + kt, t<6
        int kt = t & 1, nt = t >> 1;
        int k = kt * 32 + (l >> 4) * 8 + i;
        int n = nt * 16 + (l & 15);
        float v = (k < 40 && n < 40) ? hw2_w1[k * 40 + n] : 0.f;
        ws16[BP2_OFF + j] = f2bf(v);
    } else if (idx < 81920 + 20480 + 3072 + 160) {
        int j = idx - 105472;
        int seg = j / 40, c = j - seg * 40;
        const float* b = (seg == 0) ? hw1_b0 : (seg == 1) ? hb1_b : (seg == 2) ? hw2_b0 : hb2_b0;
        bias0[j] = b[c];
    }
}

// ---- LDS layout (bytes) ----
// SBUF [0,32768): s-tile u16[32][512] swizzled. Aliased after phase-1 consumes it:
//   W1 u16[32][324] at 0 (20736 B), PR f32[320] at 24576 (1280 B).
#define W1_STRIDE 324
#define W1_OFF    0
#define PR_OFF    24576
#define B1_OFF    32768   // 5760 : f32[32][45] (stride 45 -> conflict-free)
#define H1_OFF    38528   // 4096 : u16[32][64] swizzled (h1, K-pad)
#define H2_OFF    42624   // 4096 : u16[32][64] swizzled (h2)
#define W2_OFF    46720   // 2560 : u16[32][40]
#define B2_OFF    49280   // 256  : f32[2][32]
#define SMEM_BYTES 49536

__global__ __launch_bounds__(NTHREADS, 2) void qmix_kernel(
    const float* __restrict__ q_values, const float* __restrict__ states,
    const unsigned short* __restrict__ Bp, const unsigned short* __restrict__ Bp1,
    const unsigned short* __restrict__ Bp2, const float* __restrict__ bias0,
    const float* __restrict__ hw1_b1, const float* __restrict__ hw2_b1,
    const float* __restrict__ hb2_w1, const float* __restrict__ hb2_b1,
    float* __restrict__ out)
{
    __shared__ __align__(16) char smem[SMEM_BYTES];
    const int tid = threadIdx.x;
    const int wv = tid >> 6;
    const int l = tid & 63;
    const int p = l & 15;
    const int blkrow0 = blockIdx.x * (BROWS * TPB);

    // ---- per-block small prefetches ----
    const int c0 = wv * 32 + p, c1 = c0 + 16;
    const float bia0v = bias0[c0], bia1v = bias0[c1];
    const float hbw0 = (c0 >= 120) ? hb2_w1[c0 - 120] : 0.f;
    const float hbw1 = (c1 >= 120) ? hb2_w1[c1 - 120] : 0.f;
    float hb1v[4];
    #pragma unroll
    for (int t = 0; t < 4; ++t) hb1v[t] = hw1_b1[(wv * 4 + t) * 16 + p];
    const int n2 = wv * 16 + p;
    const float hb2v = (n2 < 40) ? hw2_b1[n2] : 0.f;
    const float hb2b = hb2_b1[0];

    // ---- zero H1/H2 K-pad (k 40..63); never overwritten afterwards ----
    for (int idx = tid; idx < 32 * 24; idx += NTHREADS) {
        int r = idx / 24, k = 40 + (idx - r * 24);
        int byte = (r * 128 + k * 2) ^ ((r & 7) << 4);
        *(unsigned short*)(smem + H1_OFF + byte) = 0;
        *(unsigned short*)(smem + H2_OFF + byte) = 0;
    }

    // ---- prologue: issue state loads for tile 0 ----
    const float4* sg = (const float4*)(states + (size_t)blkrow0 * SS);
    float4 stg[13];
    #pragma unroll
    for (int i = 0; i < 13; ++i) {
        int idx = i * NTHREADS + tid;
        if (idx < BROWS * (SS / 4)) stg[i] = sg[idx];
    }

    for (int t = 0; t < TPB; ++t) {
        const int row0 = blkrow0 + t * BROWS;
        __syncthreads();                       // A: SBUF free (prev W1/PR reads done)

        // ---- cvt staged regs -> s-tile LDS (XOR-swizzled) ----
        #pragma unroll
        for (int i = 0; i < 13; ++i) {
            int idx = i * NTHREADS + tid;
            if (idx < BROWS * (SS / 4)) {
                int r = idx >> 7, c4 = idx & 127;
                float4 v = stg[i];
                ushort4 b;
                b.x = f2bf(v.x); b.y = f2bf(v.y); b.z = f2bf(v.z); b.w = f2bf(v.w);
                int byte = (r * 1024 + c4 * 8) ^ ((r & 7) << 4);
                *(ushort4*)(smem + byte) = b;
            }
        }
        // ---- issue next tile's loads (stay in flight across compute) ----
        if (t + 1 < TPB) {
            const float4* sgn = sg + (size_t)(t + 1) * (BROWS * (SS / 4));
            #pragma unroll
            for (int i = 0; i < 13; ++i) {
                int idx = i * NTHREADS + tid;
                if (idx < BROWS * (SS / 4)) stg[i] = sgn[idx];
            }
        }
        // ---- q prefetch for this tile ----
        const float4* qp = (const float4*)(q_values + (size_t)(row0 + (tid & 31)) * NA);
        float4 qa = qp[0], qb = qp[1];
        __syncthreads();                       // B: s-tile ready

        // ---- phase 1: P[32][160] = s @ Wc via MFMA 16x16x32 bf16 ----
        f32x4 acc[2][2] = {};
        {
            const int kch = (l >> 4) * 16;
            const int r0 = p;
            const int r1 = r0 + 16;
            const int swz0 = (r0 & 7) << 4;
            const unsigned short* bp0 = Bp + (size_t)((wv * 2 + 0) * 16) * 512 + (size_t)l * 8;
            const unsigned short* bp1 = Bp + (size_t)((wv * 2 + 1) * 16) * 512 + (size_t)l * 8;
            #pragma unroll
            for (int kt = 0; kt < 16; ++kt) {
                bf16x8 a0 = *(const bf16x8*)(smem + ((r0 * 1024 + kt * 64 + kch) ^ swz0));
                bf16x8 a1 = *(const bf16x8*)(smem + ((r1 * 1024 + kt * 64 + kch) ^ swz0));
                bf16x8 b0 = *(const bf16x8*)(bp0 + kt * 512);
                bf16x8 b1 = *(const bf16x8*)(bp1 + kt * 512);
                acc[0][0] = __builtin_amdgcn_mfma_f32_16x16x32_bf16(a0, b0, acc[0][0], 0, 0, 0);
                acc[0][1] = __builtin_amdgcn_mfma_f32_16x16x32_bf16(a0, b1, acc[0][1], 0, 0, 0);
                acc[1][0] = __builtin_amdgcn_mfma_f32_16x16x32_bf16(a1, b0, acc[1][0], 0, 0, 0);
                acc[1][1] = __builtin_amdgcn_mfma_f32_16x16x32_bf16(a1, b1, acc[1][1], 0, 0, 0);
            }
        }

        // ---- phase 1 epilogue: bias+act in-register, scatter to H1/H2/B1; B2 partials ----
        {
            float rs[2][4] = {{0.f,0.f,0.f,0.f},{0.f,0.f,0.f,0.f}};
            float* b1buf = (float*)(smem + B1_OFF);
            #pragma unroll
            for (int ntl = 0; ntl < 2; ++ntl) {
                const int c = wv * 32 + ntl * 16 + p;
                const float bia = ntl ? bia1v : bia0v;
                const float hbw = ntl ? hbw1 : hbw0;
                #pragma unroll
                for (int mt = 0; mt < 2; ++mt)
                #pragma unroll
                for (int g = 0; g < 4; ++g) {
                    const int row = mt * 16 + (l >> 4) * 4 + g;
                    const float v = acc[mt][ntl][g] + bia;
                    if (c < 40) {
                        *(unsigned short*)(smem + H1_OFF + ((row * 128 + c * 2) ^ ((row & 7) << 4)))
                            = f2bf(fmaxf(v, 0.f));
                    } else if (c < 80) {
                        b1buf[row * 45 + (c - 40)] = v;
                    } else if (c < 120) {
                        *(unsigned short*)(smem + H2_OFF + ((row * 128 + (c - 80) * 2) ^ ((row & 7) << 4)))
                            = f2bf(fmaxf(v, 0.f));
                    } else {
                        rs[mt][g] += fmaxf(v, 0.f) * hbw;
                    }
                }
            }
            if (wv >= 3) {
                float* B2 = (float*)(smem + B2_OFF);
                #pragma unroll
                for (int mt = 0; mt < 2; ++mt)
                #pragma unroll
                for (int g = 0; g < 4; ++g) {
                    float r2 = rs[mt][g];
                    r2 += __shfl_xor(r2, 1);
                    r2 += __shfl_xor(r2, 2);
                    r2 += __shfl_xor(r2, 4);
                    r2 += __shfl_xor(r2, 8);
                    if (p == 0) B2[(wv - 3) * 32 + mt * 16 + (l >> 4) * 4 + g] = r2;
                }
            }
        }
        __syncthreads();                       // C

        // ---- phase 4: w1 = abs(h1 @ hw1_w1 + b) via MFMA; w2 likewise ----
        {
            char* H1 = smem + H1_OFF;
            const int kch = (l >> 4) * 16;
            f32x4 wacc[2][4] = {};
            #pragma unroll
            for (int kt = 0; kt < 2; ++kt) {
                bf16x8 a[2];
                #pragma unroll
                for (int mt = 0; mt < 2; ++mt) {
                    int row = mt * 16 + p;
                    a[mt] = *(const bf16x8*)(H1 + ((row * 128 + kt * 64 + kch) ^ ((row & 7) << 4)));
                }
                #pragma unroll
                for (int tt = 0; tt < 4; ++tt) {
                    int nt1 = wv * 4 + tt;
                    bf16x8 b = *(const bf16x8*)(Bp1 + ((size_t)(nt1 * 2 + kt) * 64 + l) * 8);
                    wacc[0][tt] = __builtin_amdgcn_mfma_f32_16x16x32_bf16(a[0], b, wacc[0][tt], 0, 0, 0);
                    wacc[1][tt] = __builtin_amdgcn_mfma_f32_16x16x32_bf16(a[1], b, wacc[1][tt], 0, 0, 0);
                }
            }
            unsigned short* W1 = (unsigned short*)(smem + W1_OFF);  // s-tile dead
            #pragma unroll
            for (int mt = 0; mt < 2; ++mt)
            #pragma unroll
            for (int tt = 0; tt < 4; ++tt)
            #pragma unroll
            for (int g = 0; g < 4; ++g) {
                int row = mt * 16 + (l >> 4) * 4 + g;
                int n = (wv * 4 + tt) * 16 + p;
                W1[row * W1_STRIDE + n] = f2bf(fabsf(wacc[mt][tt][g] + hb1v[tt]));
            }
            if (wv < 3) {
                char* H2 = smem + H2_OFF;
                f32x4 c2[2] = {};
                #pragma unroll
                for (int kt = 0; kt < 2; ++kt) {
                    bf16x8 a[2];
                    #pragma unroll
                    for (int mt = 0; mt < 2; ++mt) {
                        int row = mt * 16 + p;
                        a[mt] = *(const bf16x8*)(H2 + ((row * 128 + kt * 64 + kch) ^ ((row & 7) << 4)));
                    }
                    bf16x8 b = *(const bf16x8*)(Bp2 + ((size_t)(wv * 2 + kt) * 64 + l) * 8);
                    c2[0] = __builtin_amdgcn_mfma_f32_16x16x32_bf16(a[0], b, c2[0], 0, 0, 0);
                    c2[1] = __builtin_amdgcn_mfma_f32_16x16x32_bf16(a[1], b, c2[1], 0, 0, 0);
                }
                unsigned short* W2 = (unsigned short*)(smem + W2_OFF);
                #pragma unroll
                for (int mt = 0; mt < 2; ++mt)
                #pragma unroll
                for (int g = 0; g < 4; ++g) {
                    int row = mt * 16 + (l >> 4) * 4 + g;
                    int n = wv * 16 + p;
                    if (n < 40) W2[row * 40 + n] = f2bf(fabsf(c2[mt][g] + hb2v));
                }
            }
        }
        __syncthreads();                       // D

        // ---- phase 5: hidden = elu(q @ w1 + b1); q_total partials ----
        {
            float* b1buf = (float*)(smem + B1_OFF);
            unsigned short* W1 = (unsigned short*)(smem + W1_OFF);
            unsigned short* W2 = (unsigned short*)(smem + W2_OFF);
            float* PR = (float*)(smem + PR_OFF);
            const int r = tid & 31;
            const int gq = tid >> 5;
            float qv[8] = {qa.x, qa.y, qa.z, qa.w, qb.x, qb.y, qb.z, qb.w};
            float psum = 0.f;
            #pragma unroll
            for (int kk = 0; kk < 4; ++kk) {
                int h = gq * 4 + kk;
                float acc2 = b1buf[r * 45 + h];
                #pragma unroll
                for (int a = 0; a < 8; ++a) acc2 += qv[a] * bf2f(W1[r * W1_STRIDE + a * 40 + h]);
                float hid = (acc2 > 0.f) ? acc2 : expm1f(acc2);
                psum += hid * bf2f(W2[r * 40 + h]);
            }
            PR[tid] = psum;
        }
        __syncthreads();                       // E
        if (tid < 32) {
            float* PR = (float*)(smem + PR_OFF);
            float* B2 = (float*)(smem + B2_OFF);
            float s = B2[tid] + B2[32 + tid] + hb2b;
            #pragma unroll
            for (int g = 0; g < 10; ++g) s += PR[g * 32 + tid];
            out[row0 + tid] = s;
        }
    }
}

extern "C" void kernel_launch(void* const* d_in, const int* in_sizes, int n_in,
                              void* d_out, int out_size, void* d_ws, size_t ws_size,
                              hipStream_t stream) {
    const float* q_values = (const float*)d_in[0];
    const float* states   = (const float*)d_in[1];
    const float* hw1_w0 = (const float*)d_in[2];
    const float* hw1_b0 = (const float*)d_in[3];
    const float* hw1_w1 = (const float*)d_in[4];
    const float* hw1_b1 = (const float*)d_in[5];
    const float* hw2_w0 = (const float*)d_in[6];
    const float* hw2_b0 = (const float*)d_in[7];
    const float* hw2_w1 = (const float*)d_in[8];
    const float* hw2_b1 = (const float*)d_in[9];
    const float* hb1_w  = (const float*)d_in[10];
    const float* hb1_b  = (const float*)d_in[11];
    const float* hb2_w0 = (const float*)d_in[12];
    const float* hb2_b0 = (const float*)d_in[13];
    const float* hb2_w1 = (const float*)d_in[14];
    const float* hb2_b1 = (const float*)d_in[15];

    unsigned short* ws16 = (unsigned short*)d_ws;
    float* bias0 = (float*)((char*)d_ws + BIAS0_BYTE);

    const int prep_total = 81920 + 20480 + 3072 + 160;
    prep_kernel<<<(prep_total + 255) / 256, 256, 0, stream>>>(
        hw1_w0, hb1_w, hw2_w0, hb2_w0, hw1_w1, hw2_w1,
        hw1_b0, hb1_b, hw2_b0, hb2_b0, ws16, bias0);

    const int B = in_sizes[0] / NA;   // 65536 rows
    qmix_kernel<<<B / (BROWS * TPB), NTHREADS, 0, stream>>>(
        q_values, states,
        ws16 + BP_OFF, ws16 + BP1_OFF, ws16 + BP2_OFF, bias0,
        hw1_b1, hw2_b1, hb2_w1, hb2_b1, (float*)d_out);
}

// Round 6
// 263.625 us; speedup vs baseline: 1.5173x; 1.5173x over previous
//
#include <hip/hip_runtime.h>
#include <math.h>

#define NA 8
#define SS 512

typedef __attribute__((ext_vector_type(8))) short bf16x8;
typedef __attribute__((ext_vector_type(4))) float f32x4;

static __device__ __forceinline__ unsigned short f2bf(float f) {
    union { float f; unsigned u; } v; v.f = f;
    unsigned r = v.u + 0x7FFFu + ((v.u >> 16) & 1u);
    return (unsigned short)(r >> 16);
}
static __device__ __forceinline__ float bf2f(unsigned short u) {
    union { unsigned u; float f; } v; v.u = ((unsigned)u) << 16; return v.f;
}
// pack two f32 -> 2x bf16 (round-half-up): 5 VALU per pair
static __device__ __forceinline__ unsigned pkhu(float x, float y) {
    union { float f; unsigned u; } a, b; a.f = x; b.f = y;
    return ((a.u + 0x8000u) >> 16) | ((b.u + 0x8000u) & 0xFFFF0000u);
}

// ---- workspace layout (u16 units unless noted) ----
#define BP_OFF   0          // 81920 u16 : packed [512x160] fused first-layer W, bf16 frag layout
#define BP1_OFF  81920      // 20480 u16 : packed hw1_w1 [40->64 pad][320]
#define BP2_OFF  102400     // 3072 u16  : packed hw2_w1 [40->64 pad][40->48 pad]
#define BIAS0_BYTE 210944   // 160 f32   : fused first-layer bias [h1_b|b1_b|h2_b|hb_b]

__global__ void prep_kernel(const float* __restrict__ hw1_w0, const float* __restrict__ hb1_w,
                            const float* __restrict__ hw2_w0, const float* __restrict__ hb2_w0,
                            const float* __restrict__ hw1_w1, const float* __restrict__ hw2_w1,
                            const float* __restrict__ hw1_b0, const float* __restrict__ hb1_b,
                            const float* __restrict__ hw2_b0, const float* __restrict__ hb2_b0,
                            unsigned short* __restrict__ ws16, float* __restrict__ bias0) {
    int idx = blockIdx.x * blockDim.x + threadIdx.x;
    if (idx < 81920) {
        // Bp[((nt*16+kt)*64 + l)*8 + i] = Wc[kt*32+(l>>4)*8+i][nt*16+(l&15)]
        int i = idx & 7, l = (idx >> 3) & 63, t = idx >> 9;
        int kt = t & 15, nt = t >> 4;
        int k = kt * 32 + (l >> 4) * 8 + i;
        int n = nt * 16 + (l & 15);
        int seg = n / 40, c = n - seg * 40;
        const float* src = (seg == 0) ? hw1_w0 : (seg == 1) ? hb1_w : (seg == 2) ? hw2_w0 : hb2_w0;
        ws16[BP_OFF + idx] = f2bf(src[k * 40 + c]);
    } else if (idx < 81920 + 20480) {
        int j = idx - 81920;
        int i = j & 7, l = (j >> 3) & 63, t = j >> 9;   // t = nt1*2 + kt, t<40
        int kt = t & 1, nt = t >> 1;
        int k = kt * 32 + (l >> 4) * 8 + i;
        int n = nt * 16 + (l & 15);
        float v = (k < 40) ? hw1_w1[k * 320 + n] : 0.f;
        ws16[BP1_OFF + j] = f2bf(v);
    } else if (idx < 81920 + 20480 + 3072) {
        int j = idx - 102400;
        int i = j & 7, l = (j >> 3) & 63, t = j >> 9;   // t = nt2*2 + kt, t<6
        int kt = t & 1, nt = t >> 1;
        int k = kt * 32 + (l >> 4) * 8 + i;
        int n = nt * 16 + (l & 15);
        float v = (k < 40 && n < 40) ? hw2_w1[k * 40 + n] : 0.f;
        ws16[BP2_OFF + j] = f2bf(v);
    } else if (idx < 81920 + 20480 + 3072 + 160) {
        int j = idx - 105472;
        int seg = j / 40, c = j - seg * 40;
        const float* b = (seg == 0) ? hw1_b0 : (seg == 1) ? hb1_b : (seg == 2) ? hw2_b0 : hb2_b0;
        bias0[j] = b[c];
    }
}

// ---- LDS layout (bytes), per 1-wave block ----
#define LDS_H1 0        // 2048 : u16[16][64] swizzled (h1, K-pad to 64)
#define LDS_H2 2048     // 2048 : u16[16][64] swizzled (h2)
#define LDS_B1 4096     // 2624 : f32[16][41] (b1, stride 41)
#define LDS_W2 6720     // 1280 : u16[16][40]
#define LDS_QB 8000     // 512  : f32[16][8]
#define SMEM_BYTES 8512

__global__ __launch_bounds__(64, 4) void qmix_kernel(
    const float* __restrict__ q_values, const float* __restrict__ states,
    const unsigned short* __restrict__ Bp, const unsigned short* __restrict__ Bp1,
    const unsigned short* __restrict__ Bp2, const float* __restrict__ bias0,
    const float* __restrict__ hw1_b1, const float* __restrict__ hw2_b1,
    const float* __restrict__ hb2_w1, const float* __restrict__ hb2_b1,
    float* __restrict__ out)
{
    __shared__ __align__(16) char smem[SMEM_BYTES];
    const int l = threadIdx.x;        // one wave
    const int s = l & 15;
    const int g4 = l >> 4;
    const int row0 = blockIdx.x * 16;

    // ---- stage q tile to LDS ----
    if (l < 32) {
        float4 v = *(const float4*)(q_values + (size_t)row0 * NA + l * 4);
        *(float4*)(smem + LDS_QB + l * 16) = v;
    }
    // ---- zero H1/H2 K-pad (k 40..63) ----
    #pragma unroll
    for (int i = 0; i < 6; ++i) {
        int idx = i * 64 + l;                     // 0..383 = 16 rows * 24
        int r = idx / 24, k = 40 + idx % 24;
        int byte = (r * 128 + k * 2) ^ ((r & 7) << 4);
        *(unsigned short*)(smem + LDS_H1 + byte) = 0;
        *(unsigned short*)(smem + LDS_H2 + byte) = 0;
    }

    // ---- prologue: A rows -> bf16 fragments in registers (window-4 pipeline) ----
    const float* Ap = states + (size_t)(row0 + s) * SS + g4 * 8;
    bf16x8 aB[16];
    {
        float4 wx[4], wy[4];
        #pragma unroll
        for (int d = 0; d < 4; ++d) {
            wx[d] = *(const float4*)(Ap + d * 32);
            wy[d] = *(const float4*)(Ap + d * 32 + 4);
        }
        #pragma unroll
        for (int kt = 0; kt < 16; ++kt) {
            float4 x = wx[kt & 3], y = wy[kt & 3];
            if (kt + 4 < 16) {
                wx[kt & 3] = *(const float4*)(Ap + (kt + 4) * 32);
                wy[kt & 3] = *(const float4*)(Ap + (kt + 4) * 32 + 4);
            }
            union { bf16x8 v; unsigned u[4]; } t;
            t.u[0] = pkhu(x.x, x.y); t.u[1] = pkhu(x.z, x.w);
            t.u[2] = pkhu(y.x, y.y); t.u[3] = pkhu(y.z, y.w);
            aB[kt] = t.v;
        }
    }

    float rs[4] = {0.f, 0.f, 0.f, 0.f};           // b2 partials (hb segment)

    // ---- phase 1: P = s @ Wc in two 80-col halves (bias via C-init) ----
    #pragma unroll
    for (int half = 0; half < 2; ++half) {
        f32x4 acc[5];
        #pragma unroll
        for (int n = 0; n < 5; ++n) {
            float bv = bias0[(5 * half + n) * 16 + s];
            acc[n] = (f32x4){bv, bv, bv, bv};
        }
        const unsigned short* bp = Bp + ((size_t)(5 * half) * 16 * 64 + l) * 8;
        __builtin_amdgcn_s_setprio(1);
        #pragma unroll
        for (int n = 0; n < 5; ++n) {
            #pragma unroll
            for (int kt = 0; kt < 16; ++kt) {
                bf16x8 b = *(const bf16x8*)(bp + (size_t)(n * 16 + kt) * 512);
                acc[n] = __builtin_amdgcn_mfma_f32_16x16x32_bf16(aB[kt], b, acc[n], 0, 0, 0);
            }
        }
        __builtin_amdgcn_s_setprio(0);

        if (half == 0) {
            float* B1 = (float*)(smem + LDS_B1);
            #pragma unroll
            for (int n = 0; n < 5; ++n) {
                int c = n * 16 + s;
                #pragma unroll
                for (int g = 0; g < 4; ++g) {
                    int row = g4 * 4 + g;
                    float v = acc[n][g];
                    if (c < 40) {
                        int byte = (row * 128 + c * 2) ^ ((row & 7) << 4);
                        *(unsigned short*)(smem + LDS_H1 + byte) = f2bf(fmaxf(v, 0.f));
                    } else {
                        B1[row * 41 + (c - 40)] = v;
                    }
                }
            }
        } else {
            #pragma unroll
            for (int n = 0; n < 5; ++n) {
                int c = 80 + n * 16 + s;
                float hw = (c >= 120) ? hb2_w1[c - 120] : 0.f;
                #pragma unroll
                for (int g = 0; g < 4; ++g) {
                    int row = g4 * 4 + g;
                    float v = acc[n][g];
                    if (c < 120) {
                        int byte = (row * 128 + (c - 80) * 2) ^ ((row & 7) << 4);
                        *(unsigned short*)(smem + LDS_H2 + byte) = f2bf(fmaxf(v, 0.f));
                    } else {
                        rs[g] += fmaxf(v, 0.f) * hw;
                    }
                }
            }
            #pragma unroll
            for (int g = 0; g < 4; ++g) {
                rs[g] += __shfl_xor(rs[g], 1);
                rs[g] += __shfl_xor(rs[g], 2);
                rs[g] += __shfl_xor(rs[g], 4);
                rs[g] += __shfl_xor(rs[g], 8);
            }
        }
    }

    // ---- phase B: A-fragments of h1/h2 from LDS (swizzled; K-pad x 0-weights = 0) ----
    bf16x8 a1[2], a2[2];
    #pragma unroll
    for (int kt = 0; kt < 2; ++kt) {
        int byte = (s * 128 + kt * 64 + g4 * 16) ^ ((s & 7) << 4);
        a1[kt] = *(const bf16x8*)(smem + LDS_H1 + byte);
        a2[kt] = *(const bf16x8*)(smem + LDS_H2 + byte);
    }

    // ---- w2 = |h2 @ hw2_w1 + b| -> W2 LDS ----
    {
        unsigned short* W2 = (unsigned short*)(smem + LDS_W2);
        #pragma unroll
        for (int nt = 0; nt < 3; ++nt) {
            int c = nt * 16 + s;
            float bv = (c < 40) ? hw2_b1[c] : 0.f;
            f32x4 wa = (f32x4){bv, bv, bv, bv};
            wa = __builtin_amdgcn_mfma_f32_16x16x32_bf16(
                a2[0], *(const bf16x8*)(Bp2 + ((size_t)(nt * 2 + 0) * 64 + l) * 8), wa, 0, 0, 0);
            wa = __builtin_amdgcn_mfma_f32_16x16x32_bf16(
                a2[1], *(const bf16x8*)(Bp2 + ((size_t)(nt * 2 + 1) * 64 + l) * 8), wa, 0, 0, 0);
            if (c < 40) {
                #pragma unroll
                for (int g = 0; g < 4; ++g)
                    W2[(g4 * 4 + g) * 40 + c] = f2bf(fabsf(wa[g]));
            }
        }
    }

    // ---- w1 via in-register buckets: bucket[g][k] = sum_a q[r][a]*|w1[r][(l&7)+8k + 40a]| (own-half part) ----
    float bucket[4][5] = {};
    {
        const float* QB = (const float*)(smem + LDS_QB);
        const bool lo = (s < 8);
        #pragma unroll
        for (int ap = 0; ap < 4; ++ap) {
            #pragma unroll
            for (int j = 0; j < 5; ++j) {
                const int nt = ap * 5 + j;
                const int k0 = (2 * j) % 5;           // slot if s<8
                const int k1 = (2 * j + 1) % 5;       // slot if s>=8
                const int fl0c = (j >= 3) ? 1 : 0;    // floor((16j+s)/40), s<8
                const int fl1c = (j >= 2) ? 1 : 0;    // s>=8
                int c = nt * 16 + s;
                float bv = hw1_b1[c];
                f32x4 wa = (f32x4){bv, bv, bv, bv};
                wa = __builtin_amdgcn_mfma_f32_16x16x32_bf16(
                    a1[0], *(const bf16x8*)(Bp1 + ((size_t)(nt * 2 + 0) * 64 + l) * 8), wa, 0, 0, 0);
                wa = __builtin_amdgcn_mfma_f32_16x16x32_bf16(
                    a1[1], *(const bf16x8*)(Bp1 + ((size_t)(nt * 2 + 1) * 64 + l) * 8), wa, 0, 0, 0);
                int a = 2 * ap + (lo ? fl0c : fl1c);
                #pragma unroll
                for (int g = 0; g < 4; ++g) {
                    float w = fabsf(wa[g]);
                    float qv = QB[(g4 * 4 + g) * 8 + a];
                    float p = qv * w;
                    float p0 = lo ? p : 0.f;
                    bucket[g][k0] += p0;              // static indices; dual-slot predicated add
                    bucket[g][k1] += (p - p0);
                }
            }
        }
    }
    // partner exchange completes all 8 a-terms per (r,h)
    #pragma unroll
    for (int g = 0; g < 4; ++g)
        #pragma unroll
        for (int k = 0; k < 5; ++k)
            bucket[g][k] += __shfl_xor(bucket[g][k], 8);

    // ---- phase 5: hidden = elu(bucket + b1); q_total ----
    {
        const float* B1 = (const float*)(smem + LDS_B1);
        const unsigned short* W2 = (const unsigned short*)(smem + LDS_W2);
        float ps[4] = {0.f, 0.f, 0.f, 0.f};
        #pragma unroll
        for (int g = 0; g < 4; ++g) {
            int r = g4 * 4 + g;
            #pragma unroll
            for (int k = 0; k < 5; ++k) {
                int h = (l & 7) + 8 * k;
                float val = bucket[g][k] + B1[r * 41 + h];
                float hid = (val > 0.f) ? val : expm1f(val);
                ps[g] += hid * bf2f(W2[r * 40 + h]);
            }
        }
        #pragma unroll
        for (int g = 0; g < 4; ++g) {
            ps[g] += __shfl_xor(ps[g], 1);
            ps[g] += __shfl_xor(ps[g], 2);
            ps[g] += __shfl_xor(ps[g], 4);
        }
        if (s == 0) {
            float hb2b = hb2_b1[0];
            #pragma unroll
            for (int g = 0; g < 4; ++g)
                out[row0 + g4 * 4 + g] = ps[g] + rs[g] + hb2b;
        }
    }
}

extern "C" void kernel_launch(void* const* d_in, const int* in_sizes, int n_in,
                              void* d_out, int out_size, void* d_ws, size_t ws_size,
                              hipStream_t stream) {
    const float* q_values = (const float*)d_in[0];
    const float* states   = (const float*)d_in[1];
    const float* hw1_w0 = (const float*)d_in[2];
    const float* hw1_b0 = (const float*)d_in[3];
    const float* hw1_w1 = (const float*)d_in[4];
    const float* hw1_b1 = (const float*)d_in[5];
    const float* hw2_w0 = (const float*)d_in[6];
    const float* hw2_b0 = (const float*)d_in[7];
    const float* hw2_w1 = (const float*)d_in[8];
    const float* hw2_b1 = (const float*)d_in[9];
    const float* hb1_w  = (const float*)d_in[10];
    const float* hb1_b  = (const float*)d_in[11];
    const float* hb2_w0 = (const float*)d_in[12];
    const float* hb2_b0 = (const float*)d_in[13];
    const float* hb2_w1 = (const float*)d_in[14];
    const float* hb2_b1 = (const float*)d_in[15];

    unsigned short* ws16 = (unsigned short*)d_ws;
    float* bias0 = (float*)((char*)d_ws + BIAS0_BYTE);

    const int prep_total = 81920 + 20480 + 3072 + 160;
    prep_kernel<<<(prep_total + 255) / 256, 256, 0, stream>>>(
        hw1_w0, hb1_w, hw2_w0, hb2_w0, hw1_w1, hw2_w1,
        hw1_b0, hb1_b, hw2_b0, hb2_b0, ws16, bias0);

    const int B = in_sizes[0] / NA;   // 65536 rows
    qmix_kernel<<<B / 16, 64, 0, stream>>>(
        q_values, states,
        ws16 + BP_OFF, ws16 + BP1_OFF, ws16 + BP2_OFF, bias0,
        hw1_b1, hw2_b1, hb2_w1, hb2_b1, (float*)d_out);
}